// Round 1
// baseline (882.047 us; speedup 1.0000x reference)
//
#include <hip/hip_runtime.h>
#include <math.h>

#define N_NODES 100000
#define N_EDGES 1600000
#define D_FEAT 64
#define EPS 1e-7f

// ---- order-preserving float<->uint encoding for atomicMax on floats ----
__device__ __forceinline__ unsigned enc_f32(float f) {
    unsigned u = __float_as_uint(f);
    return (u & 0x80000000u) ? ~u : (u | 0x80000000u);
}
__device__ __forceinline__ float dec_f32(unsigned u) {
    u = (u & 0x80000000u) ? (u & 0x7FFFFFFFu) : ~u;
    return __uint_as_float(u);
}

// Zero out[] (out_size elems), encmax[] and segsum[] (N_NODES each).
__global__ void init_kernel(float* __restrict__ out, unsigned* __restrict__ encmax,
                            float* __restrict__ segsum, int total_out) {
    int i = blockIdx.x * blockDim.x + threadIdx.x;
    if (i < total_out) out[i] = 0.0f;
    if (i < N_NODES) { encmax[i] = 0u; segsum[i] = 0.0f; }
}

// One wave (64 lanes) per node: nrm[i] = ||x[i]||
__global__ void norm_kernel(const float* __restrict__ x, float* __restrict__ nrm) {
    int node = blockIdx.x * (blockDim.x >> 6) + (threadIdx.x >> 6);
    int lane = threadIdx.x & 63;
    if (node >= N_NODES) return;
    float v = x[node * D_FEAT + lane];
    float s = v * v;
    #pragma unroll
    for (int m = 1; m < 64; m <<= 1) s += __shfl_xor(s, m);
    if (lane == 0) nrm[node] = sqrtf(s);
}

// One wave per edge: sim = beta * cos(x[row], x[col]); segment max by row.
__global__ void sim_kernel(const float* __restrict__ x, const int* __restrict__ row,
                           const int* __restrict__ col, const float* __restrict__ beta_p,
                           const float* __restrict__ nrm, float* __restrict__ sim,
                           unsigned* __restrict__ encmax) {
    int e = blockIdx.x * (blockDim.x >> 6) + (threadIdx.x >> 6);
    int lane = threadIdx.x & 63;
    if (e >= N_EDGES) return;
    int r = row[e], c = col[e];
    float a = x[(long)r * D_FEAT + lane];
    float b = x[(long)c * D_FEAT + lane];
    float s = a * b;
    #pragma unroll
    for (int m = 1; m < 64; m <<= 1) s += __shfl_xor(s, m);
    if (lane == 0) {
        float denom = nrm[r] * nrm[c] + EPS;
        float sv = beta_p[0] * (s / denom);
        sim[e] = sv;
        atomicMax(&encmax[r], enc_f32(sv));
    }
}

// One thread per edge: e = exp(sim - segmax[row]); segsum[row] += e; sim <- e
__global__ void expsum_kernel(const int* __restrict__ row, float* __restrict__ sim,
                              const unsigned* __restrict__ encmax,
                              float* __restrict__ segsum) {
    int e = blockIdx.x * blockDim.x + threadIdx.x;
    if (e >= N_EDGES) return;
    int r = row[e];
    float m = dec_f32(encmax[r]);
    float ex = expf(sim[e] - m);
    sim[e] = ex;
    atomicAdd(&segsum[r], ex);
}

// One wave per edge: P = e/segsum[row]; out[col] += x[row] * P
__global__ void scatter_kernel(const float* __restrict__ x, const int* __restrict__ row,
                               const int* __restrict__ col, const float* __restrict__ sim,
                               const float* __restrict__ segsum, float* __restrict__ out) {
    int e = blockIdx.x * (blockDim.x >> 6) + (threadIdx.x >> 6);
    int lane = threadIdx.x & 63;
    if (e >= N_EDGES) return;
    int r = row[e], c = col[e];
    float P = sim[e] / segsum[r];
    float v = x[(long)r * D_FEAT + lane] * P;
    atomicAdd(&out[(long)c * D_FEAT + lane], v);
}

extern "C" void kernel_launch(void* const* d_in, const int* in_sizes, int n_in,
                              void* d_out, int out_size, void* d_ws, size_t ws_size,
                              hipStream_t stream) {
    const float* x      = (const float*)d_in[0];
    const int*   row    = (const int*)d_in[1];
    const int*   col    = (const int*)d_in[2];
    const float* beta_p = (const float*)d_in[3];
    float* out = (float*)d_out;

    // workspace layout
    char* ws = (char*)d_ws;
    float*    sim    = (float*)ws;                                   // E floats
    unsigned* encmax = (unsigned*)(ws + (size_t)N_EDGES * 4);        // N u32
    float*    segsum = (float*)(ws + (size_t)N_EDGES * 4 + (size_t)N_NODES * 4);
    float*    nrm    = (float*)(ws + (size_t)N_EDGES * 4 + (size_t)N_NODES * 8);

    const int B = 256;
    // init: covers out_size (>= N_NODES)
    int init_grid = (out_size + B - 1) / B;
    init_kernel<<<init_grid, B, 0, stream>>>(out, encmax, segsum, out_size);

    int nodes_per_blk = B / 64;
    int norm_grid = (N_NODES + nodes_per_blk - 1) / nodes_per_blk;
    norm_kernel<<<norm_grid, B, 0, stream>>>(x, nrm);

    int edges_per_blk = B / 64;
    int edge_grid = (N_EDGES + edges_per_blk - 1) / edges_per_blk;
    sim_kernel<<<edge_grid, B, 0, stream>>>(x, row, col, beta_p, nrm, sim, encmax);

    int exp_grid = (N_EDGES + B - 1) / B;
    expsum_kernel<<<exp_grid, B, 0, stream>>>(row, sim, encmax, segsum);

    scatter_kernel<<<edge_grid, B, 0, stream>>>(x, row, col, sim, segsum, out);
}